// Round 1
// baseline (1646.582 us; speedup 1.0000x reference)
//
#include <hip/hip_runtime.h>
#include <hip/hip_bf16.h>

// Problem constants (fixed by setup_inputs)
#define T_TOK 4096
#define H_DIM 1024
#define E_EXP 32
#define TOPK 4
#define CAP 1024           // T*K//E*2
#define PAIRS (T_TOK*TOPK) // 16384

__device__ __forceinline__ float bf16_bits_to_f32(unsigned short h) {
    unsigned int b = ((unsigned int)h) << 16;
    return __uint_as_float(b);
}

// ---------------- zero out-region ----------------
__global__ void zero_kernel(float4* __restrict__ p, int n4) {
    int i = blockIdx.x * blockDim.x + threadIdx.x;
    if (i < n4) p[i] = make_float4(0.f, 0.f, 0.f, 0.f);
}

// ---------------- router: logits, top-4, softmax, scores ----------------
__global__ __launch_bounds__(256) void router_kernel(
    const float* __restrict__ x,    // (T,H)
    const float* __restrict__ rw,   // (E,H)
    const float* __restrict__ rb,   // (E)
    float* __restrict__ scores,     // (T,E) -> d_out tail
    int* __restrict__ flat_e,       // (PAIRS)
    float* __restrict__ flat_w)     // (PAIRS)
{
    __shared__ float xs[H_DIM];
    __shared__ float lg[E_EXP];
    __shared__ float sw[TOPK];
    __shared__ int   se[TOPK];
    const int t = blockIdx.x;
    const int tid = threadIdx.x;

    for (int i = tid; i < H_DIM; i += 256) xs[i] = x[(size_t)t * H_DIM + i];
    __syncthreads();

    // 8 lanes per expert
    const int e = tid >> 3;
    const int l8 = tid & 7;
    float partial = 0.f;
    const float* wr = rw + (size_t)e * H_DIM;
    for (int h = l8; h < H_DIM; h += 8) partial += xs[h] * wr[h];
    partial += __shfl_xor(partial, 1);
    partial += __shfl_xor(partial, 2);
    partial += __shfl_xor(partial, 4);
    if (l8 == 0) lg[e] = partial + rb[e];
    __syncthreads();

    if (tid == 0) {
        unsigned used = 0;
        float bv[TOPK]; int bi[TOPK];
        #pragma unroll
        for (int j = 0; j < TOPK; j++) {
            float best = -1e30f; int bid = -1;
            for (int q = 0; q < E_EXP; q++) {
                if (used & (1u << q)) continue;
                if (lg[q] > best) { best = lg[q]; bid = q; }
            }
            used |= 1u << bid;
            bv[j] = best; bi[j] = bid;
        }
        const float m = bv[0];
        float s = 0.f; float w[TOPK];
        #pragma unroll
        for (int j = 0; j < TOPK; j++) { w[j] = expf(bv[j] - m); s += w[j]; }
        const float inv = 1.f / s;
        #pragma unroll
        for (int j = 0; j < TOPK; j++) { sw[j] = w[j] * inv; se[j] = bi[j]; }
    }
    __syncthreads();

    if (tid < E_EXP) {
        float v = 0.f;
        #pragma unroll
        for (int j = 0; j < TOPK; j++) if (se[j] == tid) v = sw[j];
        scores[(size_t)t * E_EXP + tid] = v;
    }
    if (tid < TOPK) {
        flat_e[t * TOPK + tid] = se[tid];
        flat_w[t * TOPK + tid] = sw[tid];
    }
}

// ---------------- deterministic rank scan (matches flattened cumsum) ----------------
__global__ __launch_bounds__(256) void scan_kernel(
    const int* __restrict__ flat_e, const float* __restrict__ flat_w,
    int* __restrict__ slot_token, float* __restrict__ slot_w,
    int* __restrict__ counts)
{
    __shared__ int cnt[256 * E_EXP]; // 32 KB
    const int tid = threadIdx.x;
    for (int e = 0; e < E_EXP; e++) cnt[tid * E_EXP + e] = 0;
    __syncthreads();
    const int base = tid * (PAIRS / 256); // 64 pairs/thread
    for (int i = 0; i < PAIRS / 256; i++) {
        int e = flat_e[base + i];
        cnt[tid * E_EXP + e]++;
    }
    __syncthreads();
    if (tid < E_EXP) {
        int run = 0;
        for (int i = 0; i < 256; i++) {
            int idx = i * E_EXP + tid;
            int v = cnt[idx];
            cnt[idx] = run;
            run += v;
        }
        counts[tid] = min(run, CAP);
    }
    __syncthreads();
    for (int i = 0; i < PAIRS / 256; i++) {
        int p = base + i;
        int e = flat_e[p];
        int r = cnt[tid * E_EXP + e]++;
        if (r < CAP) {
            slot_token[e * CAP + r] = p >> 2; // token id
            slot_w[e * CAP + r] = flat_w[p];
        }
    }
}

// ---------------- gate_up GEMM + activation -> bf16 act ----------------
// tile: 64 rows x 128 gu-cols (=64 f-cols), BK=32
__global__ __launch_bounds__(256) void gateup_kernel(
    const float* __restrict__ x,    // (T,H)
    const float* __restrict__ wgu,  // (E,H,2H)
    const float* __restrict__ gub,  // (E,2H)
    const int* __restrict__ slot_token,
    const int* __restrict__ counts,
    __hip_bfloat16* __restrict__ act) // (E,CAP,H)
{
    const int e = blockIdx.z, rt = blockIdx.y, ct = blockIdx.x;
    const int n = min(counts[e], CAP);
    const int row0 = rt * 64;
    if (row0 >= n) return;
    const int rows_here = min(64, n - row0);
    const int c0 = ct * 128; // gu-col base

    __shared__ float xs[64][33];
    __shared__ float wsd[32][128];
    __shared__ int tok[64];

    const int tid = threadIdx.x;
    if (tid < 64) {
        tok[tid] = (tid < rows_here) ? slot_token[e * CAP + row0 + tid] : -1;
    }
    __syncthreads();

    float accg[4][4] = {{0}}, accu[4][4] = {{0}};
    const int rg = tid >> 4, cg = tid & 15;

    for (int k0 = 0; k0 < H_DIM; k0 += 32) {
        // x tile: 64 x 32 = 512 float4
        for (int l = tid; l < 512; l += 256) {
            int r = l >> 3, q = l & 7;
            int tk = tok[r];
            float4 v = make_float4(0.f, 0.f, 0.f, 0.f);
            if (tk >= 0) v = *(const float4*)(x + (size_t)tk * H_DIM + k0 + q * 4);
            xs[r][q * 4 + 0] = v.x; xs[r][q * 4 + 1] = v.y;
            xs[r][q * 4 + 2] = v.z; xs[r][q * 4 + 3] = v.w;
        }
        // w tile: 32 x 128 = 1024 float4
        for (int l = tid; l < 1024; l += 256) {
            int r = l >> 5, q = l & 31;
            *(float4*)&wsd[r][q * 4] =
                *(const float4*)(wgu + ((size_t)e * H_DIM + k0 + r) * 2048 + c0 + q * 4);
        }
        __syncthreads();
        for (int k = 0; k < 32; k++) {
            float xv[4];
            #pragma unroll
            for (int i = 0; i < 4; i++) xv[i] = xs[rg * 4 + i][k];
            #pragma unroll
            for (int j = 0; j < 4; j++) {
                float2 w2 = *(const float2*)&wsd[k][(cg * 4 + j) * 2];
                #pragma unroll
                for (int i = 0; i < 4; i++) {
                    accg[i][j] = fmaf(xv[i], w2.x, accg[i][j]);
                    accu[i][j] = fmaf(xv[i], w2.y, accu[i][j]);
                }
            }
        }
        __syncthreads();
    }

    #pragma unroll
    for (int j = 0; j < 4; j++) {
        const int f = (c0 >> 1) + cg * 4 + j;
        const float bg = gub[(size_t)e * 2048 + 2 * f];
        const float bu = gub[(size_t)e * 2048 + 2 * f + 1];
        #pragma unroll
        for (int i = 0; i < 4; i++) {
            const int r = rg * 4 + i;
            if (r >= rows_here) continue;
            float g = accg[i][j] + bg;
            float u = accu[i][j] + bu;
            g = fminf(g, 7.0f);
            u = fminf(fmaxf(u, -7.0f), 7.0f);
            float glu = g / (1.0f + __expf(-g * 1.702f));
            float a = (u + 1.0f) * glu;
            act[((size_t)e * CAP + row0 + r) * H_DIM + f] = __float2bfloat16(a);
        }
    }
}

// ---------------- down GEMM + weighted atomic scatter ----------------
// tile: 64 rows x 64 cols, BK=32
__global__ __launch_bounds__(256) void down_kernel(
    const __hip_bfloat16* __restrict__ act, // (E,CAP,H)
    const float* __restrict__ wd,  // (E,H,H)
    const float* __restrict__ db,  // (E,H)
    const int* __restrict__ slot_token,
    const float* __restrict__ slot_w,
    const int* __restrict__ counts,
    float* __restrict__ out)       // (T,H)
{
    const int e = blockIdx.z, rt = blockIdx.y, ct = blockIdx.x;
    const int n = min(counts[e], CAP);
    const int row0 = rt * 64;
    if (row0 >= n) return;
    const int rows_here = min(64, n - row0);
    const int c0 = ct * 64;

    __shared__ float as[64][33];
    __shared__ float wsd[32][64];
    __shared__ int tok[64];
    __shared__ float wrow[64];

    const int tid = threadIdx.x;
    if (tid < 64) {
        if (tid < rows_here) {
            tok[tid]  = slot_token[e * CAP + row0 + tid];
            wrow[tid] = slot_w[e * CAP + row0 + tid];
        } else { tok[tid] = -1; wrow[tid] = 0.f; }
    }
    __syncthreads();

    float acc[4][4] = {{0}};
    const int rg = tid >> 4, cg = tid & 15;

    for (int k0 = 0; k0 < H_DIM; k0 += 32) {
        // a tile: 64 rows x 32 k (bf16 -> f32), one uint4 (8 bf16) per thread
        {
            int r = tid >> 2, q = tid & 3;
            float v[8];
            if (r < rows_here) {
                uint4 u = *(const uint4*)(act + ((size_t)e * CAP + row0 + r) * H_DIM + k0 + q * 8);
                unsigned int ws4[4] = {u.x, u.y, u.z, u.w};
                #pragma unroll
                for (int m = 0; m < 4; m++) {
                    v[2 * m]     = bf16_bits_to_f32((unsigned short)(ws4[m] & 0xFFFF));
                    v[2 * m + 1] = bf16_bits_to_f32((unsigned short)(ws4[m] >> 16));
                }
            } else {
                #pragma unroll
                for (int m = 0; m < 8; m++) v[m] = 0.f;
            }
            #pragma unroll
            for (int m = 0; m < 8; m++) as[r][q * 8 + m] = v[m];
        }
        // w tile: 32 x 64 = 512 float4, 2 per thread
        for (int l = tid; l < 512; l += 256) {
            int r = l >> 4, q = l & 15;
            *(float4*)&wsd[r][q * 4] =
                *(const float4*)(wd + ((size_t)e * H_DIM + k0 + r) * H_DIM + c0 + q * 4);
        }
        __syncthreads();
        for (int k = 0; k < 32; k++) {
            float xv[4];
            #pragma unroll
            for (int i = 0; i < 4; i++) xv[i] = as[rg * 4 + i][k];
            float4 w4 = *(const float4*)&wsd[k][cg * 4];
            #pragma unroll
            for (int i = 0; i < 4; i++) {
                acc[i][0] = fmaf(xv[i], w4.x, acc[i][0]);
                acc[i][1] = fmaf(xv[i], w4.y, acc[i][1]);
                acc[i][2] = fmaf(xv[i], w4.z, acc[i][2]);
                acc[i][3] = fmaf(xv[i], w4.w, acc[i][3]);
            }
        }
        __syncthreads();
    }

    #pragma unroll
    for (int i = 0; i < 4; i++) {
        const int r = rg * 4 + i;
        if (r >= rows_here) continue;
        const int t = tok[r];
        const float wv = wrow[r];
        #pragma unroll
        for (int j = 0; j < 4; j++) {
            const int col = c0 + cg * 4 + j;
            float val = acc[i][j] + db[(size_t)e * H_DIM + col];
            atomicAdd(out + (size_t)t * H_DIM + col, wv * val);
        }
    }
}

extern "C" void kernel_launch(void* const* d_in, const int* in_sizes, int n_in,
                              void* d_out, int out_size, void* d_ws, size_t ws_size,
                              hipStream_t stream) {
    const float* x   = (const float*)d_in[0];
    const float* rw  = (const float*)d_in[1];
    const float* rb  = (const float*)d_in[2];
    const float* wgu = (const float*)d_in[3];
    const float* gub = (const float*)d_in[4];
    const float* wd  = (const float*)d_in[5];
    const float* db  = (const float*)d_in[6];

    float* out    = (float*)d_out;                      // (T,H)
    float* scores = out + (size_t)T_TOK * H_DIM;        // (T,E)

    char* ws = (char*)d_ws;
    __hip_bfloat16* act = (__hip_bfloat16*)ws;          // E*CAP*H bf16 = 64 MB
    size_t off = (size_t)E_EXP * CAP * H_DIM * 2;
    int*   flat_e     = (int*)(ws + off);   off += PAIRS * 4;
    float* flat_w     = (float*)(ws + off); off += PAIRS * 4;
    int*   slot_token = (int*)(ws + off);   off += E_EXP * CAP * 4;
    float* slot_w     = (float*)(ws + off); off += E_EXP * CAP * 4;
    int*   counts     = (int*)(ws + off);   off += E_EXP * 4;
    (void)ws_size; (void)out_size; (void)n_in; (void)in_sizes;

    // zero the accumulation output region (T*H floats = 1,048,576 float4)
    hipLaunchKernelGGL(zero_kernel, dim3(4096), dim3(256), 0, stream,
                       (float4*)out, (T_TOK * H_DIM) / 4);
    hipLaunchKernelGGL(router_kernel, dim3(T_TOK), dim3(256), 0, stream,
                       x, rw, rb, scores, flat_e, flat_w);
    hipLaunchKernelGGL(scan_kernel, dim3(1), dim3(256), 0, stream,
                       flat_e, flat_w, slot_token, slot_w, counts);
    hipLaunchKernelGGL(gateup_kernel, dim3(16, 16, 32), dim3(256), 0, stream,
                       x, wgu, gub, slot_token, counts, act);
    hipLaunchKernelGGL(down_kernel, dim3(16, 16, 32), dim3(256), 0, stream,
                       act, wd, db, slot_token, slot_w, counts, out);
}

// Round 2
// 502.616 us; speedup vs baseline: 3.2760x; 3.2760x over previous
//
#include <hip/hip_runtime.h>
#include <hip/hip_bf16.h>

// Problem constants (fixed by setup_inputs)
#define T_TOK 4096
#define H_DIM 1024
#define E_EXP 32
#define TOPK 4
#define CAP 1024           // T*K//E*2
#define PAIRS (T_TOK*TOPK) // 16384

typedef __attribute__((ext_vector_type(8))) short short8v;
typedef __attribute__((ext_vector_type(4))) short short4v;
typedef __attribute__((ext_vector_type(4))) float f32x4;
typedef unsigned long long u64;

__device__ __forceinline__ unsigned bf16r(float f) {
    unsigned u = __float_as_uint(f);
    return ((u + 0x7fffu + ((u >> 16) & 1u)) >> 16) & 0xffffu;
}
__device__ __forceinline__ u64 pack4bf(float a, float b, float c, float d) {
    return (u64)(bf16r(a) | (bf16r(b) << 16)) |
           ((u64)(bf16r(c) | (bf16r(d) << 16)) << 32);
}

// ---------------- zero out-region ----------------
__global__ void zero_kernel(float4* __restrict__ p, int n4) {
    int i = blockIdx.x * blockDim.x + threadIdx.x;
    if (i < n4) p[i] = make_float4(0.f, 0.f, 0.f, 0.f);
}

// ---------------- router: logits, top-4, softmax, scores ----------------
__global__ __launch_bounds__(256) void router_kernel(
    const float* __restrict__ x,    // (T,H)
    const float* __restrict__ rw,   // (E,H)
    const float* __restrict__ rb,   // (E)
    float* __restrict__ scores,     // (T,E) -> d_out tail
    int* __restrict__ flat_e,       // (PAIRS)
    float* __restrict__ flat_w)     // (PAIRS)
{
    __shared__ float xs[H_DIM];
    __shared__ float lg[E_EXP];
    __shared__ float sw[TOPK];
    __shared__ int   se[TOPK];
    const int t = blockIdx.x;
    const int tid = threadIdx.x;

    for (int i = tid; i < H_DIM; i += 256) xs[i] = x[(size_t)t * H_DIM + i];
    __syncthreads();

    const int e = tid >> 3;
    const int l8 = tid & 7;
    float partial = 0.f;
    const float* wr = rw + (size_t)e * H_DIM;
    for (int h = l8; h < H_DIM; h += 8) partial += xs[h] * wr[h];
    partial += __shfl_xor(partial, 1);
    partial += __shfl_xor(partial, 2);
    partial += __shfl_xor(partial, 4);
    if (l8 == 0) lg[e] = partial + rb[e];
    __syncthreads();

    if (tid == 0) {
        unsigned used = 0;
        float bv[TOPK]; int bi[TOPK];
        #pragma unroll
        for (int j = 0; j < TOPK; j++) {
            float best = -1e30f; int bid = -1;
            for (int q = 0; q < E_EXP; q++) {
                if (used & (1u << q)) continue;
                if (lg[q] > best) { best = lg[q]; bid = q; }
            }
            used |= 1u << bid;
            bv[j] = best; bi[j] = bid;
        }
        const float m = bv[0];
        float s = 0.f; float w[TOPK];
        #pragma unroll
        for (int j = 0; j < TOPK; j++) { w[j] = expf(bv[j] - m); s += w[j]; }
        const float inv = 1.f / s;
        #pragma unroll
        for (int j = 0; j < TOPK; j++) { sw[j] = w[j] * inv; se[j] = bi[j]; }
    }
    __syncthreads();

    if (tid < E_EXP) {
        float v = 0.f;
        #pragma unroll
        for (int j = 0; j < TOPK; j++) if (se[j] == tid) v = sw[j];
        scores[(size_t)t * E_EXP + tid] = v;
    }
    if (tid < TOPK) {
        flat_e[t * TOPK + tid] = se[tid];
        flat_w[t * TOPK + tid] = sw[tid];
    }
}

// ---------------- deterministic rank scan (matches flattened cumsum) ----------------
__global__ __launch_bounds__(256) void scan_kernel(
    const int* __restrict__ flat_e, const float* __restrict__ flat_w,
    int* __restrict__ slot_token, float* __restrict__ slot_w,
    int* __restrict__ counts)
{
    __shared__ int cnt[256 * E_EXP]; // 32 KB
    const int tid = threadIdx.x;
    for (int e = 0; e < E_EXP; e++) cnt[tid * E_EXP + e] = 0;
    __syncthreads();
    const int base = tid * (PAIRS / 256); // 64 pairs/thread
    for (int i = 0; i < PAIRS / 256; i++) {
        int e = flat_e[base + i];
        cnt[tid * E_EXP + e]++;
    }
    __syncthreads();
    if (tid < E_EXP) {
        int run = 0;
        for (int i = 0; i < 256; i++) {
            int idx = i * E_EXP + tid;
            int v = cnt[idx];
            cnt[idx] = run;
            run += v;
        }
        counts[tid] = min(run, CAP);
    }
    __syncthreads();
    for (int i = 0; i < PAIRS / 256; i++) {
        int p = base + i;
        int e = flat_e[p];
        int r = cnt[tid * E_EXP + e]++;
        if (r < CAP) {
            slot_token[e * CAP + r] = p >> 2; // token id
            slot_w[e * CAP + r] = flat_w[p];
        }
    }
}

// ---------------- gate_up MFMA GEMM + activation -> bf16 act ----------------
// block tile: 128 rows x 64 f-cols (=128 gu-cols), BK=32, 4 waves (2x2)
__global__ __launch_bounds__(256, 2) void gateup_mfma(
    const float* __restrict__ x,     // (T,H)
    const float* __restrict__ wgu,   // (E,H,2H)
    const float* __restrict__ gub,   // (E,2H)
    const int* __restrict__ slot_token,
    const int* __restrict__ counts,
    short* __restrict__ act)         // (E,CAP,H) bf16 bits
{
    // XCD-grouped decode: 8 rt-siblings (same e,ct) land as consecutive
    // slots on one XCD -> share the 512KB weight panel in that L2.
    const int lin = blockIdx.x;
    const int xcd = lin & 7, slot = lin >> 3;
    const int gg = (slot >> 3) * 8 + xcd;   // [0,512)
    const int rt = slot & 7;
    const int e = gg >> 4, ct = gg & 15;

    const int n = counts[e];
    const int row0 = rt * 128;
    if (row0 >= n) return;
    const int rows_here = min(128, n - row0);
    const int c0f = ct * 64;    // f-col base
    const int c0gu = ct * 128;  // gu-col base

    __shared__ short As[128 * 32];     // [row][k], XOR-swizzled, 8 KB
    __shared__ short Bg[8 * 64 * 4];   // [kb][f][4k], 4 KB
    __shared__ short Bu[8 * 64 * 4];
    __shared__ int tok_s[128];

    const int tid = threadIdx.x;
    if (tid < 128)
        tok_s[tid] = (tid < rows_here) ? slot_token[e * CAP + row0 + tid] : -1;
    __syncthreads();

    const int lane = tid & 63, wid = tid >> 6;
    const int wr = wid >> 1, wc = wid & 1;
    const int l15 = lane & 15, l4 = lane >> 4;

    f32x4 accg[4][2], accu[4][2];
    #pragma unroll
    for (int m = 0; m < 4; m++)
        #pragma unroll
        for (int j = 0; j < 2; j++) { accg[m][j] = (f32x4)0.f; accu[m][j] = (f32x4)0.f; }

    float4 av[4];
    float2 bgv[2][4];

    auto prefetch = [&](int k0) {
        #pragma unroll
        for (int i = 0; i < 4; ++i) {
            int lin2 = tid + 256 * i;
            int r = lin2 >> 3, kq = lin2 & 7;
            int tk = tok_s[r];
            av[i] = (tk >= 0) ? *(const float4*)(x + (size_t)tk * H_DIM + k0 + kq * 4)
                              : make_float4(0.f, 0.f, 0.f, 0.f);
        }
        #pragma unroll
        for (int u = 0; u < 2; ++u) {
            int lin2 = tid + 256 * u;
            int f = lin2 & 63, kq = lin2 >> 6;
            const float* src = wgu + ((size_t)e * H_DIM + k0 + kq * 4) * 2048 + c0gu + 2 * f;
            #pragma unroll
            for (int q = 0; q < 4; ++q) bgv[u][q] = *(const float2*)(src + (size_t)q * 2048);
        }
    };
    auto stage = [&]() {
        #pragma unroll
        for (int i = 0; i < 4; ++i) {
            int lin2 = tid + 256 * i;
            int r = lin2 >> 3, kq = lin2 & 7;
            int dst = (r * 64 + kq * 8) ^ ((r & 3) << 4);
            *(u64*)((char*)As + dst) = pack4bf(av[i].x, av[i].y, av[i].z, av[i].w);
        }
        #pragma unroll
        for (int u = 0; u < 2; ++u) {
            int lin2 = tid + 256 * u;
            int f = lin2 & 63, kq = lin2 >> 6;
            *(u64*)((char*)Bg + kq * 512 + f * 8) =
                pack4bf(bgv[u][0].x, bgv[u][1].x, bgv[u][2].x, bgv[u][3].x);
            *(u64*)((char*)Bu + kq * 512 + f * 8) =
                pack4bf(bgv[u][0].y, bgv[u][1].y, bgv[u][2].y, bgv[u][3].y);
        }
    };

    prefetch(0);
    for (int t = 0; t < 32; ++t) {
        if (t) __syncthreads();
        stage();
        __syncthreads();
        if (t < 31) prefetch((t + 1) * 32);

        short8v afr[4];
        #pragma unroll
        for (int m = 0; m < 4; ++m) {
            int row = wr * 64 + m * 16 + l15;
            int off = (row * 64 + l4 * 16) ^ ((row & 3) << 4);
            afr[m] = *(short8v*)((char*)As + off);
        }
        #pragma unroll
        for (int j = 0; j < 2; ++j) {
            int f = wc * 32 + j * 16 + l15;
            short4v glo = *(short4v*)((char*)Bg + (2 * l4) * 512 + f * 8);
            short4v ghi = *(short4v*)((char*)Bg + (2 * l4 + 1) * 512 + f * 8);
            short4v ulo = *(short4v*)((char*)Bu + (2 * l4) * 512 + f * 8);
            short4v uhi = *(short4v*)((char*)Bu + (2 * l4 + 1) * 512 + f * 8);
            short8v bg8 = __builtin_shufflevector(glo, ghi, 0, 1, 2, 3, 4, 5, 6, 7);
            short8v bu8 = __builtin_shufflevector(ulo, uhi, 0, 1, 2, 3, 4, 5, 6, 7);
            #pragma unroll
            for (int m = 0; m < 4; ++m) {
                accg[m][j] = __builtin_amdgcn_mfma_f32_16x16x32_bf16(afr[m], bg8, accg[m][j], 0, 0, 0);
                accu[m][j] = __builtin_amdgcn_mfma_f32_16x16x32_bf16(afr[m], bu8, accu[m][j], 0, 0, 0);
            }
        }
    }

    // epilogue: bias + clamp + GLU, store bf16 act
    #pragma unroll
    for (int j = 0; j < 2; ++j) {
        int f = c0f + wc * 32 + j * 16 + l15;
        float bgb = gub[(size_t)e * 2048 + 2 * f];
        float bub = gub[(size_t)e * 2048 + 2 * f + 1];
        #pragma unroll
        for (int m = 0; m < 4; ++m) {
            int rbase = wr * 64 + m * 16 + l4 * 4;
            #pragma unroll
            for (int reg = 0; reg < 4; ++reg) {
                int r = rbase + reg;
                if (r >= rows_here) continue;
                float g = accg[m][j][reg] + bgb;
                float u = accu[m][j][reg] + bub;
                g = fminf(g, 7.0f);
                u = fminf(fmaxf(u, -7.0f), 7.0f);
                float glu = g / (1.0f + __expf(-1.702f * g));
                float a = (u + 1.0f) * glu;
                act[((size_t)e * CAP + row0 + r) * H_DIM + f] = (short)bf16r(a);
            }
        }
    }
}

// ---------------- down MFMA GEMM + weighted atomic scatter ----------------
// block tile: 128 rows x 128 cols, BK=32, 4 waves (2x2)
__global__ __launch_bounds__(256, 2) void down_mfma(
    const short* __restrict__ act,  // (E,CAP,H) bf16 bits
    const float* __restrict__ wd,   // (E,H,H)
    const float* __restrict__ db,   // (E,H)
    const int* __restrict__ slot_token,
    const float* __restrict__ slot_w,
    const int* __restrict__ counts,
    float* __restrict__ out)        // (T,H)
{
    const int lin = blockIdx.x;
    const int xcd = lin & 7, slot = lin >> 3;
    const int gg = (slot >> 3) * 8 + xcd;   // [0,256)
    const int rt = slot & 7;
    const int e = gg >> 3, ct = gg & 7;

    const int n = counts[e];
    const int row0 = rt * 128;
    if (row0 >= n) return;
    const int rows_here = min(128, n - row0);
    const int c0 = ct * 128;

    __shared__ short As[128 * 32];    // XOR-swizzled
    __shared__ short Bs[8 * 128 * 4]; // [kb][n][4k], 8 KB
    __shared__ int tok_s[128];
    __shared__ float wrow_s[128];

    const int tid = threadIdx.x;
    if (tid < 128) {
        if (tid < rows_here) {
            tok_s[tid] = slot_token[e * CAP + row0 + tid];
            wrow_s[tid] = slot_w[e * CAP + row0 + tid];
        } else { tok_s[tid] = 0; wrow_s[tid] = 0.f; }
    }
    __syncthreads();

    const int lane = tid & 63, wid = tid >> 6;
    const int wr = wid >> 1, wc = wid & 1;
    const int l15 = lane & 15, l4 = lane >> 4;

    f32x4 acc[4][4];
    #pragma unroll
    for (int m = 0; m < 4; m++)
        #pragma unroll
        for (int j = 0; j < 4; j++) acc[m][j] = (f32x4)0.f;

    uint4 avd[2];
    float2 bvd[2][4];

    auto prefetch = [&](int k0) {
        #pragma unroll
        for (int i = 0; i < 2; ++i) {
            int lin2 = tid + 256 * i;
            int r = lin2 >> 2, o = lin2 & 3;
            avd[i] = (r < rows_here)
                ? *(const uint4*)(act + ((size_t)e * CAP + row0 + r) * H_DIM + k0 + o * 8)
                : make_uint4(0, 0, 0, 0);
        }
        #pragma unroll
        for (int u = 0; u < 2; ++u) {
            int lin2 = tid + 256 * u;
            int np = lin2 & 63, kq = lin2 >> 6;
            const float* src = wd + ((size_t)e * H_DIM + k0 + kq * 4) * H_DIM + c0 + 2 * np;
            #pragma unroll
            for (int q = 0; q < 4; ++q) bvd[u][q] = *(const float2*)(src + (size_t)q * H_DIM);
        }
    };
    auto stage = [&]() {
        #pragma unroll
        for (int i = 0; i < 2; ++i) {
            int lin2 = tid + 256 * i;
            int r = lin2 >> 2, o = lin2 & 3;
            int dst = (r * 64 + o * 16) ^ ((r & 3) << 4);
            *(uint4*)((char*)As + dst) = avd[i];
        }
        #pragma unroll
        for (int u = 0; u < 2; ++u) {
            int lin2 = tid + 256 * u;
            int np = lin2 & 63, kq = lin2 >> 6;
            int n0 = 2 * np;
            *(u64*)((char*)Bs + kq * 1024 + n0 * 8) =
                pack4bf(bvd[u][0].x, bvd[u][1].x, bvd[u][2].x, bvd[u][3].x);
            *(u64*)((char*)Bs + kq * 1024 + n0 * 8 + 8) =
                pack4bf(bvd[u][0].y, bvd[u][1].y, bvd[u][2].y, bvd[u][3].y);
        }
    };

    prefetch(0);
    for (int t = 0; t < 32; ++t) {
        if (t) __syncthreads();
        stage();
        __syncthreads();
        if (t < 31) prefetch((t + 1) * 32);

        short8v afr[4];
        #pragma unroll
        for (int m = 0; m < 4; ++m) {
            int row = wr * 64 + m * 16 + l15;
            int off = (row * 64 + l4 * 16) ^ ((row & 3) << 4);
            afr[m] = *(short8v*)((char*)As + off);
        }
        #pragma unroll
        for (int j = 0; j < 4; ++j) {
            int nn = wc * 64 + j * 16 + l15;
            short4v lo = *(short4v*)((char*)Bs + (2 * l4) * 1024 + nn * 8);
            short4v hi = *(short4v*)((char*)Bs + (2 * l4 + 1) * 1024 + nn * 8);
            short8v b8 = __builtin_shufflevector(lo, hi, 0, 1, 2, 3, 4, 5, 6, 7);
            #pragma unroll
            for (int m = 0; m < 4; ++m)
                acc[m][j] = __builtin_amdgcn_mfma_f32_16x16x32_bf16(afr[m], b8, acc[m][j], 0, 0, 0);
        }
    }

    // epilogue: bias + weighted atomic scatter
    #pragma unroll
    for (int j = 0; j < 4; ++j) {
        int col = c0 + wc * 64 + j * 16 + l15;
        float bias = db[(size_t)e * H_DIM + col];
        #pragma unroll
        for (int m = 0; m < 4; ++m) {
            int rbase = wr * 64 + m * 16 + l4 * 4;
            #pragma unroll
            for (int reg = 0; reg < 4; ++reg) {
                int r = rbase + reg;
                if (r >= rows_here) continue;
                atomicAdd(out + (size_t)tok_s[r] * H_DIM + col,
                          wrow_s[r] * (acc[m][j][reg] + bias));
            }
        }
    }
}

extern "C" void kernel_launch(void* const* d_in, const int* in_sizes, int n_in,
                              void* d_out, int out_size, void* d_ws, size_t ws_size,
                              hipStream_t stream) {
    const float* x   = (const float*)d_in[0];
    const float* rw  = (const float*)d_in[1];
    const float* rb  = (const float*)d_in[2];
    const float* wgu = (const float*)d_in[3];
    const float* gub = (const float*)d_in[4];
    const float* wd  = (const float*)d_in[5];
    const float* db  = (const float*)d_in[6];

    float* out    = (float*)d_out;                  // (T,H)
    float* scores = out + (size_t)T_TOK * H_DIM;    // (T,E)

    char* ws = (char*)d_ws;
    short* act = (short*)ws;                        // E*CAP*H bf16 = 64 MB
    size_t off = (size_t)E_EXP * CAP * H_DIM * 2;
    int*   flat_e     = (int*)(ws + off);   off += PAIRS * 4;
    float* flat_w     = (float*)(ws + off); off += PAIRS * 4;
    int*   slot_token = (int*)(ws + off);   off += E_EXP * CAP * 4;
    float* slot_w     = (float*)(ws + off); off += E_EXP * CAP * 4;
    int*   counts     = (int*)(ws + off);   off += E_EXP * 4;
    (void)ws_size; (void)out_size; (void)n_in; (void)in_sizes;

    hipLaunchKernelGGL(zero_kernel, dim3(4096), dim3(256), 0, stream,
                       (float4*)out, (T_TOK * H_DIM) / 4);
    hipLaunchKernelGGL(router_kernel, dim3(T_TOK), dim3(256), 0, stream,
                       x, rw, rb, scores, flat_e, flat_w);
    hipLaunchKernelGGL(scan_kernel, dim3(1), dim3(256), 0, stream,
                       flat_e, flat_w, slot_token, slot_w, counts);
    hipLaunchKernelGGL(gateup_mfma, dim3(4096), dim3(256), 0, stream,
                       x, wgu, gub, slot_token, counts, act);
    hipLaunchKernelGGL(down_mfma, dim3(2048), dim3(256), 0, stream,
                       act, wd, db, slot_token, slot_w, counts, out);
}

// Round 3
// 494.425 us; speedup vs baseline: 3.3303x; 1.0166x over previous
//
#include <hip/hip_runtime.h>
#include <hip/hip_bf16.h>

#define T_TOK 4096
#define H_DIM 1024
#define E_EXP 32
#define TOPK 4
#define CAP 1024
#define PAIRS (T_TOK*TOPK)

typedef __attribute__((ext_vector_type(8))) short short8v;
typedef __attribute__((ext_vector_type(4))) short short4v;
typedef __attribute__((ext_vector_type(4))) float f32x4;
typedef unsigned long long u64;
typedef unsigned short ushort;

__device__ __forceinline__ float bf16_bits_to_f32(ushort h) {
    return __uint_as_float(((unsigned)h) << 16);
}
__device__ __forceinline__ unsigned bf16r(float f) {
    unsigned u = __float_as_uint(f);
    return ((u + 0x7fffu + ((u >> 16) & 1u)) >> 16) & 0xffffu;
}
// single v_cvt_pk_bf16_f32: 2 f32 -> packed 2 bf16 (RNE)
__device__ __forceinline__ unsigned cvt2(float a, float b) {
    unsigned r;
    asm("v_cvt_pk_bf16_f32 %0, %1, %2" : "=v"(r) : "v"(a), "v"(b));
    return r;
}
__device__ __forceinline__ u64 pk4(float a, float b, float c, float d) {
    return (u64)cvt2(a, b) | ((u64)cvt2(c, d) << 32);
}

#define GLD16(gsrc, ldst) \
    __builtin_amdgcn_global_load_lds( \
        (const __attribute__((address_space(1))) unsigned*)(gsrc), \
        (__attribute__((address_space(3))) unsigned*)(ldst), 16, 0, 0)

// ---------------- router ----------------
__global__ __launch_bounds__(256) void router_kernel(
    const float* __restrict__ x, const float* __restrict__ rw,
    const float* __restrict__ rb, float* __restrict__ scores,
    int* __restrict__ flat_e, float* __restrict__ flat_w)
{
    __shared__ float xs[H_DIM];
    __shared__ float lg[E_EXP];
    __shared__ float sw[TOPK];
    __shared__ int   se[TOPK];
    const int t = blockIdx.x;
    const int tid = threadIdx.x;

    for (int i = tid; i < H_DIM; i += 256) xs[i] = x[(size_t)t * H_DIM + i];
    __syncthreads();

    const int e = tid >> 3, l8 = tid & 7;
    float partial = 0.f;
    const float* wr = rw + (size_t)e * H_DIM;
    for (int h = l8; h < H_DIM; h += 8) partial += xs[h] * wr[h];
    partial += __shfl_xor(partial, 1);
    partial += __shfl_xor(partial, 2);
    partial += __shfl_xor(partial, 4);
    if (l8 == 0) lg[e] = partial + rb[e];
    __syncthreads();

    if (tid == 0) {
        unsigned used = 0;
        float bv[TOPK]; int bi[TOPK];
        #pragma unroll
        for (int j = 0; j < TOPK; j++) {
            float best = -1e30f; int bid = -1;
            for (int q = 0; q < E_EXP; q++) {
                if (used & (1u << q)) continue;
                if (lg[q] > best) { best = lg[q]; bid = q; }
            }
            used |= 1u << bid;
            bv[j] = best; bi[j] = bid;
        }
        const float m = bv[0];
        float s = 0.f; float w[TOPK];
        #pragma unroll
        for (int j = 0; j < TOPK; j++) { w[j] = expf(bv[j] - m); s += w[j]; }
        const float inv = 1.f / s;
        #pragma unroll
        for (int j = 0; j < TOPK; j++) { sw[j] = w[j] * inv; se[j] = bi[j]; }
    }
    __syncthreads();

    if (tid < E_EXP) {
        float v = 0.f;
        #pragma unroll
        for (int j = 0; j < TOPK; j++) if (se[j] == tid) v = sw[j];
        scores[(size_t)t * E_EXP + tid] = v;
    }
    if (tid < TOPK) {
        flat_e[t * TOPK + tid] = se[tid];
        flat_w[t * TOPK + tid] = sw[tid];
    }
}

// ---------------- deterministic rank scan ----------------
__global__ __launch_bounds__(256) void scan_kernel(
    const int* __restrict__ flat_e, const float* __restrict__ flat_w,
    int* __restrict__ slot_token, float* __restrict__ slot_w,
    int* __restrict__ pair_slot, int* __restrict__ counts)
{
    __shared__ int cnt[256 * E_EXP];
    const int tid = threadIdx.x;
    for (int e = 0; e < E_EXP; e++) cnt[tid * E_EXP + e] = 0;
    __syncthreads();
    const int base = tid * (PAIRS / 256);
    for (int i = 0; i < PAIRS / 256; i++) {
        int e = flat_e[base + i];
        cnt[tid * E_EXP + e]++;
    }
    __syncthreads();
    if (tid < E_EXP) {
        int run = 0;
        for (int i = 0; i < 256; i++) {
            int idx = i * E_EXP + tid;
            int v = cnt[idx];
            cnt[idx] = run;
            run += v;
        }
        counts[tid] = min(run, CAP);
    }
    __syncthreads();
    for (int i = 0; i < PAIRS / 256; i++) {
        int p = base + i;
        int e = flat_e[p];
        int r = cnt[tid * E_EXP + e]++;
        if (r < CAP) {
            slot_token[e * CAP + r] = p >> 2;
            slot_w[e * CAP + r] = flat_w[p];
            pair_slot[p] = r;
        } else {
            pair_slot[p] = -1;
        }
    }
}

// ---------------- stage tokens: gather x -> tiled+swizzled bf16 xbuf ----------------
// tile layout: (e, rt) base + kb*8192 + r*64 + ((g^(r&3))*16) + (k&7)*2
__global__ __launch_bounds__(256) void stage_tokens(
    const float* __restrict__ x, const int* __restrict__ slot_token,
    const int* __restrict__ counts, char* __restrict__ xbuf)
{
    const int e = blockIdx.y, rt = blockIdx.x;
    const int n = counts[e];
    const int row0 = rt * 128;
    if (row0 >= n) return;
    const int rows_here = min(128, n - row0);
    const int lane = threadIdx.x & 63, wv = threadIdx.x >> 6;
    char* tb = xbuf + ((size_t)(e * 8 + rt)) * 262144;

    for (int r = wv; r < rows_here; r += 4) {
        const float* xr = x + (size_t)slot_token[e * CAP + row0 + r] * H_DIM;
        #pragma unroll
        for (int q = 0; q < 2; ++q) {
            int g = q * 64 + lane;                 // granule 0..127 (8 elems each)
            float4 a = *(const float4*)(xr + g * 8);
            float4 b = *(const float4*)(xr + g * 8 + 4);
            uint4 w;
            w.x = cvt2(a.x, a.y); w.y = cvt2(a.z, a.w);
            w.z = cvt2(b.x, b.y); w.w = cvt2(b.z, b.w);
            int kb = g >> 2, gi = g & 3;
            *(uint4*)(tb + kb * 8192 + r * 64 + ((gi ^ (r & 3)) * 16)) = w;
        }
    }
}

// ---------------- gate_up MFMA GEMM + activation -> tiled bf16 act ----------------
__global__ __launch_bounds__(256, 3) void gateup_mfma(
    const char* __restrict__ xbuf,   // tiled bf16
    const float* __restrict__ wgu,   // (E,H,2H) fp32
    const float* __restrict__ gub,
    const int* __restrict__ counts,
    char* __restrict__ act)          // tiled bf16
{
    const int lin = blockIdx.x;
    const int xcd = lin & 7, slot = lin >> 3;
    const int gg = (slot >> 3) * 8 + xcd;
    const int rt = slot & 7;
    const int e = gg >> 4, ct = gg & 15;

    const int n = counts[e];
    const int row0 = rt * 128;
    if (row0 >= n) return;
    const int rows_here = min(128, n - row0);
    const int c0f = ct * 64, c0gu = ct * 128;

    __shared__ char AsB[2][8192];
    __shared__ char BgB[2][4096];
    __shared__ char BuB[2][4096];

    const int tid = threadIdx.x;
    const int lane = tid & 63, wid = tid >> 6;
    const int wr = wid >> 1, wc = wid & 1;
    const int l15 = lane & 15, l4 = lane >> 4;

    const char* xtile = xbuf + ((size_t)(e * 8 + rt)) * 262144;

    f32x4 accg[4][2], accu[4][2];
    #pragma unroll
    for (int m = 0; m < 4; m++)
        #pragma unroll
        for (int j = 0; j < 2; j++) { accg[m][j] = (f32x4)0.f; accu[m][j] = (f32x4)0.f; }

    float2 bgv[2][4];
    const int bnp = tid & 63;        // f-col within 64
    const int bkq0 = tid >> 6;       // 0..3 (u adds +4)

    auto stageA = [&](int buf, int t) {
        const char* src = xtile + (size_t)t * 8192 + wid * 2048 + lane * 16;
        char* dst = AsB[buf] + wid * 2048;
        GLD16(src, dst);
        GLD16(src + 1024, dst + 1024);
    };
    auto bload = [&](int k0) {
        #pragma unroll
        for (int u = 0; u < 2; ++u) {
            int kq = bkq0 + 4 * u;
            const float* src = wgu + ((size_t)e * H_DIM + k0 + kq * 4) * 2048 + c0gu + 2 * bnp;
            #pragma unroll
            for (int q = 0; q < 4; ++q) bgv[u][q] = *(const float2*)(src + (size_t)q * 2048);
        }
    };
    auto bpack = [&](int buf) {
        #pragma unroll
        for (int u = 0; u < 2; ++u) {
            int kq = bkq0 + 4 * u;
            *(u64*)(BgB[buf] + kq * 512 + bnp * 8) =
                pk4(bgv[u][0].x, bgv[u][1].x, bgv[u][2].x, bgv[u][3].x);
            *(u64*)(BuB[buf] + kq * 512 + bnp * 8) =
                pk4(bgv[u][0].y, bgv[u][1].y, bgv[u][2].y, bgv[u][3].y);
        }
    };

    bload(0);
    stageA(0, 0);
    bpack(0);
    __syncthreads();
    int cur = 0;

    for (int t = 0; t < 32; ++t) {
        if (t < 31) { bload((t + 1) * 32); stageA(cur ^ 1, t + 1); }

        short8v afr[4];
        #pragma unroll
        for (int m = 0; m < 4; ++m) {
            int row = wr * 64 + m * 16 + l15;
            afr[m] = *(short8v*)(AsB[cur] + row * 64 + ((l4 ^ (row & 3)) * 16));
        }
        #pragma unroll
        for (int j = 0; j < 2; ++j) {
            int f = wc * 32 + j * 16 + l15;
            short4v glo = *(short4v*)(BgB[cur] + (2 * l4) * 512 + f * 8);
            short4v ghi = *(short4v*)(BgB[cur] + (2 * l4 + 1) * 512 + f * 8);
            short4v ulo = *(short4v*)(BuB[cur] + (2 * l4) * 512 + f * 8);
            short4v uhi = *(short4v*)(BuB[cur] + (2 * l4 + 1) * 512 + f * 8);
            short8v bg8 = __builtin_shufflevector(glo, ghi, 0, 1, 2, 3, 4, 5, 6, 7);
            short8v bu8 = __builtin_shufflevector(ulo, uhi, 0, 1, 2, 3, 4, 5, 6, 7);
            #pragma unroll
            for (int m = 0; m < 4; ++m) {
                accg[m][j] = __builtin_amdgcn_mfma_f32_16x16x32_bf16(afr[m], bg8, accg[m][j], 0, 0, 0);
                accu[m][j] = __builtin_amdgcn_mfma_f32_16x16x32_bf16(afr[m], bu8, accu[m][j], 0, 0, 0);
            }
        }
        if (t < 31) bpack(cur ^ 1);
        __syncthreads();
        cur ^= 1;
    }

    // epilogue: bias + clamp + GLU -> act (tiled layout, k-dim = f)
    char* atile = act + ((size_t)(e * 8 + rt)) * 262144;
    #pragma unroll
    for (int j = 0; j < 2; ++j) {
        int f = c0f + wc * 32 + j * 16 + l15;
        float bgb = gub[(size_t)e * 2048 + 2 * f];
        float bub = gub[(size_t)e * 2048 + 2 * f + 1];
        int kb = f >> 5, gi = (f & 31) >> 3, ke = f & 7;
        #pragma unroll
        for (int m = 0; m < 4; ++m) {
            int rbase = wr * 64 + m * 16 + l4 * 4;
            #pragma unroll
            for (int reg = 0; reg < 4; ++reg) {
                int r = rbase + reg;
                if (r >= rows_here) continue;
                float g = accg[m][j][reg] + bgb;
                float u = accu[m][j][reg] + bub;
                g = fminf(g, 7.0f);
                u = fminf(fmaxf(u, -7.0f), 7.0f);
                float glu = g / (1.0f + __expf(-1.702f * g));
                float a = (u + 1.0f) * glu;
                *(ushort*)(atile + kb * 8192 + r * 64 + ((gi ^ (r & 3)) * 16) + ke * 2)
                    = (ushort)bf16r(a);
            }
        }
    }
}

// ---------------- down MFMA GEMM -> eout (bf16, linear) ----------------
__global__ __launch_bounds__(256, 3) void down_mfma(
    const char* __restrict__ act,   // tiled bf16
    const float* __restrict__ wd,   // (E,H,H) fp32
    const float* __restrict__ db,
    const int* __restrict__ counts,
    ushort* __restrict__ eout)      // (E,CAP,H) bf16 linear
{
    const int lin = blockIdx.x;
    const int xcd = lin & 7, slot = lin >> 3;
    const int gg = (slot >> 3) * 8 + xcd;
    const int rt = slot & 7;
    const int e = gg >> 3, ct = gg & 7;

    const int n = counts[e];
    const int row0 = rt * 128;
    if (row0 >= n) return;
    const int rows_here = min(128, n - row0);
    const int c0 = ct * 128;

    __shared__ char AsB[2][8192];
    __shared__ char BsB[2][8192];

    const int tid = threadIdx.x;
    const int lane = tid & 63, wid = tid >> 6;
    const int wr = wid >> 1, wc = wid & 1;
    const int l15 = lane & 15, l4 = lane >> 4;

    const char* atile = act + ((size_t)(e * 8 + rt)) * 262144;

    f32x4 acc[4][4];
    #pragma unroll
    for (int m = 0; m < 4; m++)
        #pragma unroll
        for (int j = 0; j < 4; j++) acc[m][j] = (f32x4)0.f;

    float2 bvd[2][4];
    const int bnp = tid & 63;   // n-pair (2 cols)
    const int bkq0 = tid >> 6;

    auto stageA = [&](int buf, int t) {
        const char* src = atile + (size_t)t * 8192 + wid * 2048 + lane * 16;
        char* dst = AsB[buf] + wid * 2048;
        GLD16(src, dst);
        GLD16(src + 1024, dst + 1024);
    };
    auto bload = [&](int k0) {
        #pragma unroll
        for (int u = 0; u < 2; ++u) {
            int kq = bkq0 + 4 * u;
            const float* src = wd + ((size_t)e * H_DIM + k0 + kq * 4) * H_DIM + c0 + 2 * bnp;
            #pragma unroll
            for (int q = 0; q < 4; ++q) bvd[u][q] = *(const float2*)(src + (size_t)q * H_DIM);
        }
    };
    auto bpack = [&](int buf) {
        #pragma unroll
        for (int u = 0; u < 2; ++u) {
            int kq = bkq0 + 4 * u;
            char* dst = BsB[buf] + kq * 1024 + bnp * 16;
            *(u64*)dst       = pk4(bvd[u][0].x, bvd[u][1].x, bvd[u][2].x, bvd[u][3].x);
            *(u64*)(dst + 8) = pk4(bvd[u][0].y, bvd[u][1].y, bvd[u][2].y, bvd[u][3].y);
        }
    };

    bload(0);
    stageA(0, 0);
    bpack(0);
    __syncthreads();
    int cur = 0;

    for (int t = 0; t < 32; ++t) {
        if (t < 31) { bload((t + 1) * 32); stageA(cur ^ 1, t + 1); }

        short8v afr[4];
        #pragma unroll
        for (int m = 0; m < 4; ++m) {
            int row = wr * 64 + m * 16 + l15;
            afr[m] = *(short8v*)(AsB[cur] + row * 64 + ((l4 ^ (row & 3)) * 16));
        }
        #pragma unroll
        for (int j = 0; j < 4; ++j) {
            int nn = wc * 64 + j * 16 + l15;
            short4v lo = *(short4v*)(BsB[cur] + (2 * l4) * 1024 + nn * 8);
            short4v hi = *(short4v*)(BsB[cur] + (2 * l4 + 1) * 1024 + nn * 8);
            short8v b8 = __builtin_shufflevector(lo, hi, 0, 1, 2, 3, 4, 5, 6, 7);
            #pragma unroll
            for (int m = 0; m < 4; ++m)
                acc[m][j] = __builtin_amdgcn_mfma_f32_16x16x32_bf16(afr[m], b8, acc[m][j], 0, 0, 0);
        }
        if (t < 31) bpack(cur ^ 1);
        __syncthreads();
        cur ^= 1;
    }

    // epilogue: bias, store bf16 eout rows
    #pragma unroll
    for (int j = 0; j < 4; ++j) {
        int col = c0 + wc * 64 + j * 16 + l15;
        float bias = db[(size_t)e * H_DIM + col];
        #pragma unroll
        for (int m = 0; m < 4; ++m) {
            int rbase = wr * 64 + m * 16 + l4 * 4;
            #pragma unroll
            for (int reg = 0; reg < 4; ++reg) {
                int r = rbase + reg;
                if (r >= rows_here) continue;
                eout[((size_t)e * CAP + row0 + r) * H_DIM + col] =
                    (ushort)bf16r(acc[m][j][reg] + bias);
            }
        }
    }
}

// ---------------- finalize: out[t] = sum_k w_k * eout[e_k, slot_k] ----------------
__global__ __launch_bounds__(256) void finalize_kernel(
    const ushort* __restrict__ eout, const int* __restrict__ flat_e,
    const float* __restrict__ flat_w, const int* __restrict__ pair_slot,
    float* __restrict__ out)
{
    const int t = blockIdx.x;
    const int c = threadIdx.x * 4;
    float a0 = 0.f, a1 = 0.f, a2 = 0.f, a3 = 0.f;
    #pragma unroll
    for (int k = 0; k < TOPK; ++k) {
        int p = t * TOPK + k;
        int s = pair_slot[p];
        if (s < 0) continue;
        int e = flat_e[p];
        float w = flat_w[p];
        const ushort* row = eout + ((size_t)e * CAP + s) * H_DIM + c;
        ushort4 v = *(const ushort4*)row;
        a0 += w * bf16_bits_to_f32(v.x);
        a1 += w * bf16_bits_to_f32(v.y);
        a2 += w * bf16_bits_to_f32(v.z);
        a3 += w * bf16_bits_to_f32(v.w);
    }
    *(float4*)(out + (size_t)t * H_DIM + c) = make_float4(a0, a1, a2, a3);
}

extern "C" void kernel_launch(void* const* d_in, const int* in_sizes, int n_in,
                              void* d_out, int out_size, void* d_ws, size_t ws_size,
                              hipStream_t stream) {
    const float* x   = (const float*)d_in[0];
    const float* rw  = (const float*)d_in[1];
    const float* rb  = (const float*)d_in[2];
    const float* wgu = (const float*)d_in[3];
    const float* gub = (const float*)d_in[4];
    const float* wd  = (const float*)d_in[5];
    const float* db  = (const float*)d_in[6];

    float* out    = (float*)d_out;
    float* scores = out + (size_t)T_TOK * H_DIM;

    char* ws = (char*)d_ws;
    char* xbuf = ws;                                  // 64 MB tiled bf16 (also eout)
    ushort* eout = (ushort*)ws;                       // overlay: phases serialized
    size_t off = (size_t)E_EXP * CAP * H_DIM * 2;
    char* act = ws + off;          off += (size_t)E_EXP * CAP * H_DIM * 2; // 64 MB tiled
    int*   flat_e     = (int*)(ws + off);   off += PAIRS * 4;
    float* flat_w     = (float*)(ws + off); off += PAIRS * 4;
    int*   slot_token = (int*)(ws + off);   off += E_EXP * CAP * 4;
    float* slot_w     = (float*)(ws + off); off += E_EXP * CAP * 4;
    int*   pair_slot  = (int*)(ws + off);   off += PAIRS * 4;
    int*   counts     = (int*)(ws + off);   off += E_EXP * 4;
    (void)ws_size; (void)out_size; (void)n_in; (void)in_sizes; (void)slot_w;

    hipLaunchKernelGGL(router_kernel, dim3(T_TOK), dim3(256), 0, stream,
                       x, rw, rb, scores, flat_e, flat_w);
    hipLaunchKernelGGL(scan_kernel, dim3(1), dim3(256), 0, stream,
                       flat_e, flat_w, slot_token, slot_w, pair_slot, counts);
    hipLaunchKernelGGL(stage_tokens, dim3(8, E_EXP), dim3(256), 0, stream,
                       x, slot_token, counts, xbuf);
    hipLaunchKernelGGL(gateup_mfma, dim3(4096), dim3(256), 0, stream,
                       xbuf, wgu, gub, counts, act);
    hipLaunchKernelGGL(down_mfma, dim3(2048), dim3(256), 0, stream,
                       act, wd, db, counts, eout);
    hipLaunchKernelGGL(finalize_kernel, dim3(T_TOK), dim3(256), 0, stream,
                       eout, flat_e, flat_w, pair_slot, out);
}